// Round 5
// baseline (261.659 us; speedup 1.0000x reference)
//
#include <hip/hip_runtime.h>
#include <hip/hip_bf16.h>

// ---------------------------------------------------------------------------
// SelfAttention_Conv2D: B=4, H=W=64 (n=4096), C=128.
// Round 5: attn occupancy 8->16 waves/CU + transposed S/P pipeline.
//   - 512-thread WGs (8 waves, QTILE=256 q), NSPLIT=8 -> grid (64,8),
//     LDS 72.7KB -> 2 WG/CU = 16 waves/CU. Fallback NSPLIT=4 if ws small.
//   - Compute S^T = mfma(g_frag, q_frag): C-layout col=q, row=key ->
//     P-strip write becomes 8x ds_write_b64 (was 32x scalar b16);
//     l-accum needs no per-iter shuffles (2 shfl at end).
//   - Compute O^T = mfma(v_frag, p_frag): epilogue 16x b64 (was 64x b16).
//   All LDS READ patterns identical to the round-3/4 verified kernel.
// ---------------------------------------------------------------------------

typedef __hip_bfloat16 bf16;
typedef float  floatx4 __attribute__((ext_vector_type(4)));
typedef short  shortx8 __attribute__((ext_vector_type(8)));
typedef short  shortx4 __attribute__((ext_vector_type(4)));

#define CDIM 128
#define NROW 16384            // B*n
#define NPB  4096             // n per batch
#define LDW  136              // LDS stride for 128-wide bf16 rows
#define LDK  72               // LDS stride for 64-wide bf16 rows (v tile)
#define LDP  72               // LDS stride for P strips (144B: keeps b128 16B-aligned)
#define QTILE 256             // queries per attn WG (8 waves x 32)

__device__ __forceinline__ short f2bf(float v) {
    union { __hip_bfloat16 h; short s; } u; u.h = __float2bfloat16(v); return u.s;
}
__device__ __forceinline__ float bf2f(short s) {
    union { short s2; __hip_bfloat16 h; } u; u.s2 = s; return __bfloat162float(u.h);
}

// ---------------------------------------------------------------------------
// K1: one projection matrix per WG. bid = mtx*256 + rowblk/64. (unchanged)
// ---------------------------------------------------------------------------
__global__ __launch_bounds__(256) void proj3_kernel(
    const float* __restrict__ x,
    const float* __restrict__ Wf, const float* __restrict__ bf_,
    const float* __restrict__ Wg, const float* __restrict__ bg_,
    const float* __restrict__ Wh, const float* __restrict__ bh_,
    bf16* __restrict__ f, bf16* __restrict__ g, bf16* __restrict__ vT)
{
    __shared__ bf16 wt[128 * LDW];   // wt[n][k] = W[k][n]; reused as vt bounce

    const int t    = threadIdx.x;
    const int wave = t >> 6, lane = t & 63;
    const int quad = lane >> 4, l16 = lane & 15;
    const int mtx    = blockIdx.x >> 8;
    const int rowblk = (blockIdx.x & 255) * 64;
    const int row    = rowblk + wave * 16 + l16;

    const float* Ws[3] = {Wf, Wg, Wh};
    const float* Bs[3] = {bf_, bg_, bh_};
    const float* W    = Ws[mtx];
    const float* bias = Bs[mtx];

    for (int i = t; i < 128 * 32; i += 256) {
        int k = i >> 5, n0 = (i & 31) * 4;
        floatx4 wv = *(const floatx4*)(W + k * CDIM + n0);
#pragma unroll
        for (int j = 0; j < 4; ++j)
            *(short*)&wt[(n0 + j) * LDW + k] = f2bf(wv[j]);
    }

    shortx8 afr[4];
    {
        const float* xp = x + (size_t)row * CDIM + quad * 8;
#pragma unroll
        for (int kc = 0; kc < 4; ++kc) {
            floatx4 u = *(const floatx4*)(xp + kc * 32);
            floatx4 w = *(const floatx4*)(xp + kc * 32 + 4);
            shortx8 a;
            a[0]=f2bf(u[0]); a[1]=f2bf(u[1]); a[2]=f2bf(u[2]); a[3]=f2bf(u[3]);
            a[4]=f2bf(w[0]); a[5]=f2bf(w[1]); a[6]=f2bf(w[2]); a[7]=f2bf(w[3]);
            afr[kc] = a;
        }
    }
    __syncthreads();

    floatx4 acc[8];
#pragma unroll
    for (int nt = 0; nt < 8; ++nt) acc[nt] = (floatx4){0.f, 0.f, 0.f, 0.f};
#pragma unroll
    for (int nt = 0; nt < 8; ++nt) {
        const bf16* wrow = &wt[(nt * 16 + l16) * LDW + quad * 8];
#pragma unroll
        for (int kc = 0; kc < 4; ++kc) {
            shortx8 b = *(const shortx8*)(wrow + kc * 32);
            acc[nt] = __builtin_amdgcn_mfma_f32_16x16x32_bf16(afr[kc], b, acc[nt], 0, 0, 0);
        }
    }

    if (mtx < 2) {
        bf16* dst = (mtx == 0) ? f : g;
#pragma unroll
        for (int nt = 0; nt < 8; ++nt) {
            int col = nt * 16 + l16;
            float bv_ = bias[col];
#pragma unroll
            for (int r = 0; r < 4; ++r) {
                int orow = rowblk + wave * 16 + quad * 4 + r;
                *(short*)&dst[(size_t)orow * CDIM + col] = f2bf(acc[nt][r] + bv_);
            }
        }
    } else {
        // vT via LDS bounce: coalesced global stores
        __syncthreads();
        bf16* vt = wt;
        const int nloc0 = wave * 16 + quad * 4;
#pragma unroll
        for (int nt = 0; nt < 8; ++nt) {
            int ch = nt * 16 + l16;
            float bv_ = bias[ch];
            shortx4 pk;
#pragma unroll
            for (int r = 0; r < 4; ++r) pk[r] = f2bf(acc[nt][r] + bv_);
            *(shortx4*)&vt[ch * LDK + nloc0] = pk;
        }
        __syncthreads();
        const int ch  = t >> 1;
        const int seg = (t & 1) * 32;
        const int batch = rowblk >> 12;
        const int n0 = (rowblk & 4095) + seg;
        bf16* dst = &vT[((size_t)batch * CDIM + ch) * NPB + n0];
        const bf16* src = &vt[ch * LDK + seg];
#pragma unroll
        for (int j = 0; j < 4; ++j)
            *(shortx8*)(dst + j * 8) = *(const shortx8*)(src + j * 8);
    }
}

// ---------------------------------------------------------------------------
// K2: flash attention, transposed pipeline, 512 threads (8 waves, 256 q).
// blockIdx.x = qg (0..63: b*16+qt), blockIdx.y = split (0..nsplit-1).
// ---------------------------------------------------------------------------
__global__ __launch_bounds__(512, 4) void attn_kernel(
    const bf16* __restrict__ f, const bf16* __restrict__ g,
    const bf16* __restrict__ vT,
    bf16* __restrict__ Opart, float* __restrict__ lbuf,
    int nsplit, int ktps)
{
    __shared__ bf16 gs[64 * LDW];         // g tile [key][ch]     17408 B
    __shared__ bf16 vs[128 * LDK];        // v tile [ch][key]     18432 B
    __shared__ bf16 ps[QTILE * LDP];      // P strips [q][key]    36864 B

    const int t    = threadIdx.x;
    const int wave = t >> 6, lane = t & 63;
    const int quad = lane >> 4, l16 = lane & 15;
    const int qg    = blockIdx.x;
    const int split = blockIdx.y;
    const int b  = qg >> 4;
    const int qt = qg & 15;
    const int qbase = b * NPB + qt * QTILE + wave * 32;

    // Q frags (B-operand for S^T): identical loads to round-3 verified kernel
    shortx8 qf[2][4];
#pragma unroll
    for (int sub = 0; sub < 2; ++sub) {
        const bf16* qp = f + (size_t)(qbase + sub * 16 + l16) * CDIM + quad * 8;
#pragma unroll
        for (int kc = 0; kc < 4; ++kc) qf[sub][kc] = *(const shortx8*)(qp + kc * 32);
    }

    floatx4 o[2][8];     // O^T accum: o[sub][ct] -> ch = ct*16+quad*4+r, q = sub*16+l16
#pragma unroll
    for (int sub = 0; sub < 2; ++sub)
#pragma unroll
        for (int ct = 0; ct < 8; ++ct) o[sub][ct] = (floatx4){0.f, 0.f, 0.f, 0.f};
    float lacc[2] = {0.f, 0.f};          // per-lane l partial (q = l16 fixed)

    const bf16* gptr = g + (size_t)b * NPB * CDIM;
    const bf16* vptr = vT + (size_t)b * CDIM * NPB;

    // staging coordinates (512 threads: 2 chunks each for gs and vs)
    const int gkey = t >> 4, gch = (t & 15) * 8;   // +i*32 keys
    const int vch  = t >> 3, vk0 = (t & 7) * 8;    // +i*64 ch

    shortx8 gx[2], vx[2];
    {
        const int kt = split * ktps;
#pragma unroll
        for (int i = 0; i < 2; ++i) {
            gx[i] = *(const shortx8*)&gptr[(size_t)(kt * 64 + i * 32 + gkey) * CDIM + gch];
            vx[i] = *(const shortx8*)&vptr[(size_t)(i * 64 + vch) * NPB + kt * 64 + vk0];
        }
    }

    for (int it = 0; it < ktps; ++it) {
        __syncthreads();                   // prev tile consumers done
#pragma unroll
        for (int i = 0; i < 2; ++i) {
            *(shortx8*)&gs[(i * 32 + gkey) * LDW + gch] = gx[i];
            *(shortx8*)&vs[(i * 64 + vch) * LDK + vk0] = vx[i];
        }
        if (it + 1 < ktps) {               // prefetch next tile
            const int kt = split * ktps + it + 1;
#pragma unroll
            for (int i = 0; i < 2; ++i) {
                gx[i] = *(const shortx8*)&gptr[(size_t)(kt * 64 + i * 32 + gkey) * CDIM + gch];
                vx[i] = *(const shortx8*)&vptr[(size_t)(i * 64 + vch) * NPB + kt * 64 + vk0];
            }
        }
        __syncthreads();                   // tile visible

        // ---- S^T = mfma(A=g_frag, B=q_frag): col=q (l16), row=key (nt*16+quad*4+r)
        floatx4 s[2][4];
#pragma unroll
        for (int sub = 0; sub < 2; ++sub)
#pragma unroll
            for (int nt = 0; nt < 4; ++nt) s[sub][nt] = (floatx4){0.f, 0.f, 0.f, 0.f};
#pragma unroll
        for (int nt = 0; nt < 4; ++nt) {
            const bf16* grow = &gs[(nt * 16 + l16) * LDW + quad * 8];
#pragma unroll
            for (int kc = 0; kc < 4; ++kc) {
                shortx8 gfr = *(const shortx8*)(grow + kc * 32);
                s[0][nt] = __builtin_amdgcn_mfma_f32_16x16x32_bf16(gfr, qf[0][kc], s[0][nt], 0, 0, 0);
                s[1][nt] = __builtin_amdgcn_mfma_f32_16x16x32_bf16(gfr, qf[1][kc], s[1][nt], 0, 0, 0);
            }
        }

        // ---- exp -> P strip [q][key] via packed b64 writes; per-lane l accum
#pragma unroll
        for (int sub = 0; sub < 2; ++sub) {
            bf16* pw = &ps[(wave * 32 + sub * 16 + l16) * LDP];
#pragma unroll
            for (int nt = 0; nt < 4; ++nt) {
                shortx4 pk;
                float ls = 0.f;
#pragma unroll
                for (int r = 0; r < 4; ++r) {
                    float p = __expf(s[sub][nt][r]);
                    pk[r] = f2bf(p);
                    ls += p;
                }
                *(shortx4*)&pw[nt * 16 + quad * 4] = pk;   // 4 contiguous keys
                lacc[sub] += ls;
            }
        }

        // ---- P back as B-frags (same-wave strip; lgkmcnt orders it) ----
        shortx8 pa[2][2];
#pragma unroll
        for (int sub = 0; sub < 2; ++sub) {
            const bf16* pr = &ps[(wave * 32 + sub * 16 + l16) * LDP + quad * 8];
            pa[sub][0] = *(const shortx8*)pr;
            pa[sub][1] = *(const shortx8*)(pr + 32);
        }

        // ---- O^T += mfma(A=v_frag, B=p_frag) ----
#pragma unroll
        for (int ct = 0; ct < 8; ++ct) {
            const bf16* vrow = &vs[(ct * 16 + l16) * LDK + quad * 8];
#pragma unroll
            for (int kc2 = 0; kc2 < 2; ++kc2) {
                shortx8 vfr = *(const shortx8*)(vrow + kc2 * 32);
                o[0][ct] = __builtin_amdgcn_mfma_f32_16x16x32_bf16(vfr, pa[0][kc2], o[0][ct], 0, 0, 0);
                o[1][ct] = __builtin_amdgcn_mfma_f32_16x16x32_bf16(vfr, pa[1][kc2], o[1][ct], 0, 0, 0);
            }
        }
    }

    // ---- epilogue: Opart[q][ch] packed b64 stores; l via 2 shfls ----
    const size_t pbase = ((size_t)qg * nsplit + split) * QTILE * CDIM;
#pragma unroll
    for (int sub = 0; sub < 2; ++sub) {
        const int q = wave * 32 + sub * 16 + l16;
#pragma unroll
        for (int ct = 0; ct < 8; ++ct) {
            shortx4 pk;
#pragma unroll
            for (int r = 0; r < 4; ++r) pk[r] = f2bf(o[sub][ct][r]);
            *(shortx4*)&Opart[pbase + (size_t)q * CDIM + ct * 16 + quad * 4] = pk;
        }
    }
    float* lb = lbuf + ((size_t)qg * nsplit + split) * QTILE;
#pragma unroll
    for (int sub = 0; sub < 2; ++sub) {
        float v = lacc[sub];
        v += __shfl_xor(v, 16);
        v += __shfl_xor(v, 32);
        if (quad == 0) lb[wave * 32 + sub * 16 + l16] = v;
    }
}

// ---------------------------------------------------------------------------
// K3: fused combine + output proj. ctx = (sum_s O_s)/L ; o = ctx@(gm*Wv)+bv+x
// ---------------------------------------------------------------------------
__global__ __launch_bounds__(256) void out_kernel(
    const bf16* __restrict__ Opart, const float* __restrict__ lbuf,
    const float* __restrict__ Wv, const float* __restrict__ bv,
    const float* __restrict__ x, const float* __restrict__ gamma,
    float* __restrict__ out, int nsplit)
{
    __shared__ bf16 wt[128 * LDW];

    const int t    = threadIdx.x;
    const int wave = t >> 6, lane = t & 63;
    const int quad = lane >> 4, l16 = lane & 15;
    const int rowblk = blockIdx.x * 64;
    const int row    = rowblk + wave * 16 + l16;

    const float gm = gamma[0];
    for (int i = t; i < 128 * 32; i += 256) {
        int k = i >> 5, n0 = (i & 31) * 4;
        floatx4 wv4 = *(const floatx4*)(Wv + k * CDIM + n0);
#pragma unroll
        for (int j = 0; j < 4; ++j)
            *(short*)&wt[(n0 + j) * LDW + k] = f2bf(wv4[j] * gm);
    }

    const int qg = row >> 8, rl = row & 255;   // QTILE = 256
    float L = 0.f;
    for (int s = 0; s < nsplit; ++s)
        L += lbuf[((size_t)qg * nsplit + s) * QTILE + rl];
    const float inv = 1.0f / L;

    shortx8 afr[4];
#pragma unroll
    for (int kc = 0; kc < 4; ++kc) {
        float a8[8] = {0,0,0,0,0,0,0,0};
        for (int s = 0; s < nsplit; ++s) {
            const bf16* p = &Opart[(((size_t)qg * nsplit + s) * QTILE + rl) * CDIM + quad * 8 + kc * 32];
            shortx8 v = *(const shortx8*)p;
#pragma unroll
            for (int j = 0; j < 8; ++j) a8[j] += bf2f(v[j]);
        }
        shortx8 a;
#pragma unroll
        for (int j = 0; j < 8; ++j) a[j] = f2bf(a8[j] * inv);
        afr[kc] = a;
    }
    __syncthreads();

    floatx4 acc[8];
#pragma unroll
    for (int nt = 0; nt < 8; ++nt) acc[nt] = (floatx4){0.f, 0.f, 0.f, 0.f};
#pragma unroll
    for (int nt = 0; nt < 8; ++nt) {
        const bf16* wrow = &wt[(nt * 16 + l16) * LDW + quad * 8];
#pragma unroll
        for (int kc = 0; kc < 4; ++kc) {
            shortx8 b = *(const shortx8*)(wrow + kc * 32);
            acc[nt] = __builtin_amdgcn_mfma_f32_16x16x32_bf16(afr[kc], b, acc[nt], 0, 0, 0);
        }
    }

#pragma unroll
    for (int nt = 0; nt < 8; ++nt) {
        int col = nt * 16 + l16;
        float bias = bv[col];
#pragma unroll
        for (int r = 0; r < 4; ++r) {
            int orow = rowblk + wave * 16 + quad * 4 + r;
            size_t idx = (size_t)orow * CDIM + col;
            out[idx] = acc[nt][r] + bias + x[idx];
        }
    }
}

// ---------------------------------------------------------------------------
extern "C" void kernel_launch(void* const* d_in, const int* in_sizes, int n_in,
                              void* d_out, int out_size, void* d_ws, size_t ws_size,
                              hipStream_t stream)
{
    const float* x   = (const float*)d_in[0];
    const float* Wf  = (const float*)d_in[1];
    const float* bf_ = (const float*)d_in[2];
    const float* Wg  = (const float*)d_in[3];
    const float* bg_ = (const float*)d_in[4];
    const float* Wh  = (const float*)d_in[5];
    const float* bh_ = (const float*)d_in[6];
    const float* Wv  = (const float*)d_in[7];
    const float* bv  = (const float*)d_in[8];
    const float* gm  = (const float*)d_in[9];
    float* out = (float*)d_out;

    // pick nsplit by workspace budget (deterministic across calls)
    const size_t fgv_el = (size_t)3 * NROW * CDIM;               // f,g,vT bf16
    size_t need8 = (fgv_el + (size_t)64 * 8 * QTILE * CDIM) * 2

                 + (size_t)64 * 8 * QTILE * 4;
    const int nsplit = (ws_size >= need8) ? 8 : 4;
    const int ktps   = 64 / nsplit;      // 64-key tiles per split

    bf16* f     = (bf16*)d_ws;
    bf16* g     = f + (size_t)NROW * CDIM;
    bf16* vT    = g + (size_t)NROW * CDIM;
    bf16* Opart = vT + (size_t)4 * CDIM * NPB;
    float* lbuf = (float*)(Opart + (size_t)64 * nsplit * QTILE * CDIM);

    proj3_kernel<<<768, 256, 0, stream>>>(x, Wf, bf_, Wg, bg_, Wh, bh_, f, g, vT);
    attn_kernel<<<dim3(64, nsplit), 512, 0, stream>>>(f, g, vT, Opart, lbuf, nsplit, ktps);
    out_kernel<<<256, 256, 0, stream>>>(Opart, lbuf, Wv, bv, x, gm, out, nsplit);
}

// Round 6
// 159.772 us; speedup vs baseline: 1.6377x; 1.6377x over previous
//
#include <hip/hip_runtime.h>
#include <hip/hip_bf16.h>

// ---------------------------------------------------------------------------
// SelfAttention_Conv2D: B=4, H=W=64 (n=4096), C=128.
// Round 6: revert attn to the verified round-4 body (R5's 512-thread
// launch_bounds(512,4) capped VGPR at 64 -> scratch spill -> 620MB HBM).
// Single change vs round 4: NSPLIT 4 -> 6, grid (128,6) = 768 WGs = 3 WG/CU
// (LDS 54.3KB fits 3.02; previously grid-limited to 2). Uneven K-splits
// (11/11/11/11/10/10 tiles) are fine for the no-max l-sum softmax.
// NOTE: do not cap VGPR below 3 waves/SIMD (~170) for attn — needs ~184.
// ---------------------------------------------------------------------------

typedef __hip_bfloat16 bf16;
typedef float  floatx4 __attribute__((ext_vector_type(4)));
typedef short  shortx8 __attribute__((ext_vector_type(8)));
typedef short  shortx4 __attribute__((ext_vector_type(4)));

#define CDIM 128
#define NROW 16384            // B*n
#define NPB  4096             // n per batch
#define LDW  136              // LDS stride for 128-wide bf16 rows
#define LDK  72               // LDS stride for 64-wide bf16 rows
#define QTILE 128             // queries per attn WG
#define NKT  64               // total 64-key tiles (4096 keys)

__device__ __forceinline__ short f2bf(float v) {
    union { __hip_bfloat16 h; short s; } u; u.h = __float2bfloat16(v); return u.s;
}
__device__ __forceinline__ float bf2f(short s) {
    union { short s2; __hip_bfloat16 h; } u; u.s2 = s; return __bfloat162float(u.h);
}

// ---------------------------------------------------------------------------
// K1: one projection matrix per WG. bid = mtx*256 + rowblk/64. (unchanged)
// ---------------------------------------------------------------------------
__global__ __launch_bounds__(256) void proj3_kernel(
    const float* __restrict__ x,
    const float* __restrict__ Wf, const float* __restrict__ bf_,
    const float* __restrict__ Wg, const float* __restrict__ bg_,
    const float* __restrict__ Wh, const float* __restrict__ bh_,
    bf16* __restrict__ f, bf16* __restrict__ g, bf16* __restrict__ vT)
{
    __shared__ bf16 wt[128 * LDW];   // wt[n][k] = W[k][n]; reused as vt bounce

    const int t    = threadIdx.x;
    const int wave = t >> 6, lane = t & 63;
    const int quad = lane >> 4, l16 = lane & 15;
    const int mtx    = blockIdx.x >> 8;
    const int rowblk = (blockIdx.x & 255) * 64;
    const int row    = rowblk + wave * 16 + l16;

    const float* Ws[3] = {Wf, Wg, Wh};
    const float* Bs[3] = {bf_, bg_, bh_};
    const float* W    = Ws[mtx];
    const float* bias = Bs[mtx];

    for (int i = t; i < 128 * 32; i += 256) {
        int k = i >> 5, n0 = (i & 31) * 4;
        floatx4 wv = *(const floatx4*)(W + k * CDIM + n0);
#pragma unroll
        for (int j = 0; j < 4; ++j)
            *(short*)&wt[(n0 + j) * LDW + k] = f2bf(wv[j]);
    }

    shortx8 afr[4];
    {
        const float* xp = x + (size_t)row * CDIM + quad * 8;
#pragma unroll
        for (int kc = 0; kc < 4; ++kc) {
            floatx4 u = *(const floatx4*)(xp + kc * 32);
            floatx4 w = *(const floatx4*)(xp + kc * 32 + 4);
            shortx8 a;
            a[0]=f2bf(u[0]); a[1]=f2bf(u[1]); a[2]=f2bf(u[2]); a[3]=f2bf(u[3]);
            a[4]=f2bf(w[0]); a[5]=f2bf(w[1]); a[6]=f2bf(w[2]); a[7]=f2bf(w[3]);
            afr[kc] = a;
        }
    }
    __syncthreads();

    floatx4 acc[8];
#pragma unroll
    for (int nt = 0; nt < 8; ++nt) acc[nt] = (floatx4){0.f, 0.f, 0.f, 0.f};
#pragma unroll
    for (int nt = 0; nt < 8; ++nt) {
        const bf16* wrow = &wt[(nt * 16 + l16) * LDW + quad * 8];
#pragma unroll
        for (int kc = 0; kc < 4; ++kc) {
            shortx8 b = *(const shortx8*)(wrow + kc * 32);
            acc[nt] = __builtin_amdgcn_mfma_f32_16x16x32_bf16(afr[kc], b, acc[nt], 0, 0, 0);
        }
    }

    if (mtx < 2) {
        bf16* dst = (mtx == 0) ? f : g;
#pragma unroll
        for (int nt = 0; nt < 8; ++nt) {
            int col = nt * 16 + l16;
            float bv_ = bias[col];
#pragma unroll
            for (int r = 0; r < 4; ++r) {
                int orow = rowblk + wave * 16 + quad * 4 + r;
                *(short*)&dst[(size_t)orow * CDIM + col] = f2bf(acc[nt][r] + bv_);
            }
        }
    } else {
        // vT via LDS bounce: coalesced global stores
        __syncthreads();
        bf16* vt = wt;
        const int nloc0 = wave * 16 + quad * 4;
#pragma unroll
        for (int nt = 0; nt < 8; ++nt) {
            int ch = nt * 16 + l16;
            float bv_ = bias[ch];
            shortx4 pk;
#pragma unroll
            for (int r = 0; r < 4; ++r) pk[r] = f2bf(acc[nt][r] + bv_);
            *(shortx4*)&vt[ch * LDK + nloc0] = pk;
        }
        __syncthreads();
        const int ch  = t >> 1;
        const int seg = (t & 1) * 32;
        const int batch = rowblk >> 12;
        const int n0 = (rowblk & 4095) + seg;
        bf16* dst = &vT[((size_t)batch * CDIM + ch) * NPB + n0];
        const bf16* src = &vt[ch * LDK + seg];
#pragma unroll
        for (int j = 0; j < 4; ++j)
            *(shortx8*)(dst + j * 8) = *(const shortx8*)(src + j * 8);
    }
}

// ---------------------------------------------------------------------------
// K2: flash attention (round-4 verified body). blockIdx.x = qg, .y = split.
// K-tile range [kt0, kt1) computed from split (uneven splits OK).
// ---------------------------------------------------------------------------
__global__ __launch_bounds__(256, 2) void attn_kernel(
    const bf16* __restrict__ f, const bf16* __restrict__ g,
    const bf16* __restrict__ vT,
    bf16* __restrict__ Opart, float* __restrict__ lbuf, int nsplit)
{
    __shared__ bf16 gs[64 * LDW];        // g tile [key][ch]
    __shared__ bf16 vs[128 * LDK];       // v tile [ch][key]
    __shared__ bf16 ps[4 * 32 * LDK];    // per-wave P strips [q][key]

    const int t    = threadIdx.x;
    const int wave = t >> 6, lane = t & 63;
    const int quad = lane >> 4, l16 = lane & 15;
    const int qg    = blockIdx.x;
    const int split = blockIdx.y;
    const int b  = qg >> 5;
    const int qt = qg & 31;
    const int qbase = b * NPB + qt * QTILE + wave * 32;

    const int kt0 = (split * NKT) / nsplit;
    const int kt1 = ((split + 1) * NKT) / nsplit;

    shortx8 qf[2][4];
#pragma unroll
    for (int sub = 0; sub < 2; ++sub) {
        const bf16* qp = f + (size_t)(qbase + sub * 16 + l16) * CDIM + quad * 8;
#pragma unroll
        for (int kc = 0; kc < 4; ++kc) qf[sub][kc] = *(const shortx8*)(qp + kc * 32);
    }

    floatx4 o[2][8];
#pragma unroll
    for (int sub = 0; sub < 2; ++sub)
#pragma unroll
        for (int ct = 0; ct < 8; ++ct) o[sub][ct] = (floatx4){0.f, 0.f, 0.f, 0.f};
    float lacc[2][4];
#pragma unroll
    for (int sub = 0; sub < 2; ++sub)
#pragma unroll
        for (int r = 0; r < 4; ++r) lacc[sub][r] = 0.f;

    const bf16* gptr = g + (size_t)b * NPB * CDIM;
    const bf16* vptr = vT + (size_t)b * CDIM * NPB;

    const int gkey = t >> 4, gch = (t & 15) * 8;
    const int vch  = t >> 3, vk0 = (t & 7) * 8;

    shortx8 gx[4], vx[4];
    {
#pragma unroll
        for (int i = 0; i < 4; ++i) {
            gx[i] = *(const shortx8*)&gptr[(size_t)(kt0 * 64 + i * 16 + gkey) * CDIM + gch];
            vx[i] = *(const shortx8*)&vptr[(size_t)(i * 32 + vch) * NPB + kt0 * 64 + vk0];
        }
    }

    for (int kt = kt0; kt < kt1; ++kt) {
        __syncthreads();
#pragma unroll
        for (int i = 0; i < 4; ++i) {
            *(shortx8*)&gs[(i * 16 + gkey) * LDW + gch] = gx[i];
            *(shortx8*)&vs[(i * 32 + vch) * LDK + vk0] = vx[i];
        }
        if (kt + 1 < kt1) {
            const int ktn = kt + 1;
#pragma unroll
            for (int i = 0; i < 4; ++i) {
                gx[i] = *(const shortx8*)&gptr[(size_t)(ktn * 64 + i * 16 + gkey) * CDIM + gch];
                vx[i] = *(const shortx8*)&vptr[(size_t)(i * 32 + vch) * NPB + ktn * 64 + vk0];
            }
        }
        __syncthreads();

        floatx4 s[2][4];
#pragma unroll
        for (int sub = 0; sub < 2; ++sub)
#pragma unroll
            for (int nt = 0; nt < 4; ++nt) s[sub][nt] = (floatx4){0.f, 0.f, 0.f, 0.f};
#pragma unroll
        for (int nt = 0; nt < 4; ++nt) {
            const bf16* grow = &gs[(nt * 16 + l16) * LDW + quad * 8];
#pragma unroll
            for (int kc = 0; kc < 4; ++kc) {
                shortx8 bfr = *(const shortx8*)(grow + kc * 32);
                s[0][nt] = __builtin_amdgcn_mfma_f32_16x16x32_bf16(qf[0][kc], bfr, s[0][nt], 0, 0, 0);
                s[1][nt] = __builtin_amdgcn_mfma_f32_16x16x32_bf16(qf[1][kc], bfr, s[1][nt], 0, 0, 0);
            }
        }

#pragma unroll
        for (int sub = 0; sub < 2; ++sub) {
            bf16* pw = &ps[(wave * 32 + sub * 16 + quad * 4) * LDK];
#pragma unroll
            for (int r = 0; r < 4; ++r) {
#pragma unroll
                for (int nt = 0; nt < 4; ++nt) {
                    float p = __expf(s[sub][nt][r]);
                    *(short*)&pw[r * LDK + nt * 16 + l16] = f2bf(p);
                    lacc[sub][r] += p;
                }
            }
        }

        shortx8 pa[2][2];
#pragma unroll
        for (int sub = 0; sub < 2; ++sub) {
            const bf16* pr = &ps[(wave * 32 + sub * 16 + l16) * LDK + quad * 8];
            pa[sub][0] = *(const shortx8*)pr;
            pa[sub][1] = *(const shortx8*)(pr + 32);
        }

#pragma unroll
        for (int ct = 0; ct < 8; ++ct) {
            const bf16* vrow = &vs[(ct * 16 + l16) * LDK + quad * 8];
#pragma unroll
            for (int kc2 = 0; kc2 < 2; ++kc2) {
                shortx8 bfr = *(const shortx8*)(vrow + kc2 * 32);
                o[0][ct] = __builtin_amdgcn_mfma_f32_16x16x32_bf16(pa[0][kc2], bfr, o[0][ct], 0, 0, 0);
                o[1][ct] = __builtin_amdgcn_mfma_f32_16x16x32_bf16(pa[1][kc2], bfr, o[1][ct], 0, 0, 0);
            }
        }
    }

    const size_t pbase = ((size_t)qg * nsplit + split) * QTILE * CDIM;
#pragma unroll
    for (int sub = 0; sub < 2; ++sub)
#pragma unroll
        for (int ct = 0; ct < 8; ++ct) {
            int col = ct * 16 + l16;
#pragma unroll
            for (int r = 0; r < 4; ++r) {
                int rl = wave * 32 + sub * 16 + quad * 4 + r;
                *(short*)&Opart[pbase + (size_t)rl * CDIM + col] = f2bf(o[sub][ct][r]);
            }
        }
    float* lb = lbuf + ((size_t)qg * nsplit + split) * QTILE;
#pragma unroll
    for (int sub = 0; sub < 2; ++sub)
#pragma unroll
        for (int r = 0; r < 4; ++r) {
            float v = lacc[sub][r];
            v += __shfl_xor(v, 1);
            v += __shfl_xor(v, 2);
            v += __shfl_xor(v, 4);
            v += __shfl_xor(v, 8);
            if (l16 == 0) lb[wave * 32 + sub * 16 + quad * 4 + r] = v;
        }
}

// ---------------------------------------------------------------------------
// K3: fused combine + output proj (round-4 verified, nsplit runtime).
// ---------------------------------------------------------------------------
__global__ __launch_bounds__(256) void out_kernel(
    const bf16* __restrict__ Opart, const float* __restrict__ lbuf,
    const float* __restrict__ Wv, const float* __restrict__ bv,
    const float* __restrict__ x, const float* __restrict__ gamma,
    float* __restrict__ out, int nsplit)
{
    __shared__ bf16 wt[128 * LDW];

    const int t    = threadIdx.x;
    const int wave = t >> 6, lane = t & 63;
    const int quad = lane >> 4, l16 = lane & 15;
    const int rowblk = blockIdx.x * 64;
    const int row    = rowblk + wave * 16 + l16;

    const float gm = gamma[0];
    for (int i = t; i < 128 * 32; i += 256) {
        int k = i >> 5, n0 = (i & 31) * 4;
        floatx4 wv4 = *(const floatx4*)(Wv + k * CDIM + n0);
#pragma unroll
        for (int j = 0; j < 4; ++j)
            *(short*)&wt[(n0 + j) * LDW + k] = f2bf(wv4[j] * gm);
    }

    const int qg = row >> 7, rl = row & 127;   // QTILE = 128
    float L = 0.f;
    for (int s = 0; s < nsplit; ++s)
        L += lbuf[((size_t)qg * nsplit + s) * QTILE + rl];
    const float inv = 1.0f / L;

    shortx8 afr[4];
#pragma unroll
    for (int kc = 0; kc < 4; ++kc) {
        float a8[8] = {0,0,0,0,0,0,0,0};
        for (int s = 0; s < nsplit; ++s) {
            const bf16* p = &Opart[(((size_t)qg * nsplit + s) * QTILE + rl) * CDIM + quad * 8 + kc * 32];
            shortx8 v = *(const shortx8*)p;
#pragma unroll
            for (int j = 0; j < 8; ++j) a8[j] += bf2f(v[j]);
        }
        shortx8 a;
#pragma unroll
        for (int j = 0; j < 8; ++j) a[j] = f2bf(a8[j] * inv);
        afr[kc] = a;
    }
    __syncthreads();

    floatx4 acc[8];
#pragma unroll
    for (int nt = 0; nt < 8; ++nt) acc[nt] = (floatx4){0.f, 0.f, 0.f, 0.f};
#pragma unroll
    for (int nt = 0; nt < 8; ++nt) {
        const bf16* wrow = &wt[(nt * 16 + l16) * LDW + quad * 8];
#pragma unroll
        for (int kc = 0; kc < 4; ++kc) {
            shortx8 b = *(const shortx8*)(wrow + kc * 32);
            acc[nt] = __builtin_amdgcn_mfma_f32_16x16x32_bf16(afr[kc], b, acc[nt], 0, 0, 0);
        }
    }

#pragma unroll
    for (int nt = 0; nt < 8; ++nt) {
        int col = nt * 16 + l16;
        float bias = bv[col];
#pragma unroll
        for (int r = 0; r < 4; ++r) {
            int orow = rowblk + wave * 16 + quad * 4 + r;
            size_t idx = (size_t)orow * CDIM + col;
            out[idx] = acc[nt][r] + bias + x[idx];
        }
    }
}

// ---------------------------------------------------------------------------
extern "C" void kernel_launch(void* const* d_in, const int* in_sizes, int n_in,
                              void* d_out, int out_size, void* d_ws, size_t ws_size,
                              hipStream_t stream)
{
    const float* x   = (const float*)d_in[0];
    const float* Wf  = (const float*)d_in[1];
    const float* bf_ = (const float*)d_in[2];
    const float* Wg  = (const float*)d_in[3];
    const float* bg_ = (const float*)d_in[4];
    const float* Wh  = (const float*)d_in[5];
    const float* bh_ = (const float*)d_in[6];
    const float* Wv  = (const float*)d_in[7];
    const float* bv  = (const float*)d_in[8];
    const float* gm  = (const float*)d_in[9];
    float* out = (float*)d_out;

    // nsplit=6 -> grid 768 WGs = 3 WG/CU. Fallback 4 if ws too small.
    const size_t base_el = (size_t)3 * NROW * CDIM;   // f,g,vT
    const size_t need6 = (base_el + (size_t)128 * 6 * QTILE * CDIM) * sizeof(bf16)
                       + (size_t)128 * 6 * QTILE * sizeof(float);
    const int nsplit = (ws_size >= need6) ? 6 : 4;

    bf16* f     = (bf16*)d_ws;
    bf16* g     = f + (size_t)NROW * CDIM;
    bf16* vT    = g + (size_t)NROW * CDIM;
    bf16* Opart = vT + (size_t)4 * CDIM * NPB;
    float* lbuf = (float*)(Opart + (size_t)128 * nsplit * QTILE * CDIM);

    proj3_kernel<<<768, 256, 0, stream>>>(x, Wf, bf_, Wg, bg_, Wh, bh_, f, g, vT);
    attn_kernel<<<dim3(128, nsplit), 256, 0, stream>>>(f, g, vT, Opart, lbuf, nsplit);
    out_kernel<<<256, 256, 0, stream>>>(Opart, lbuf, Wv, bv, x, gm, out, nsplit);
}